// Round 6
// baseline (594.159 us; speedup 1.0000x reference)
//
#include <hip/hip_runtime.h>
#include <hip/hip_bf16.h>
#include <float.h>

#define NEG 0.2f

__device__ __forceinline__ float leaky(float x) { return x > 0.0f ? x : NEG * x; }

__device__ __forceinline__ unsigned short f2bf(float f) {
  unsigned x = __float_as_uint(f);
  unsigned r = (x + 0x7fffu + ((x >> 16) & 1u)) >> 16;  // round-to-nearest-even
  return (unsigned short)r;
}

__device__ __forceinline__ float2 bf2f2(unsigned u) {   // u = (ch1<<16)|ch0
  float2 r;
  r.x = __uint_as_float(u << 16);
  r.y = __uint_as_float(u & 0xffff0000u);
  return r;
}

// ---------------------------------------------------------------- utilities
__global__ void zero_kernel(int* __restrict__ p, int n) {
  int i = blockIdx.x * blockDim.x + threadIdx.x;
  int stride = gridDim.x * blockDim.x;
  for (; i < n; i += stride) p[i] = 0;
}

__global__ void count_kernel(const int* __restrict__ ei, int* __restrict__ deg, int E, int N) {
  int i = blockIdx.x * blockDim.x + threadIdx.x;
  if (i >= E + N) return;
  int dst = (i < E) ? ei[E + i] : (i - E);
  atomicAdd(&deg[dst], 1);
}

__global__ __launch_bounds__(1024) void scan_block_kernel(const int* __restrict__ deg,
                                                          int* __restrict__ row_start,
                                                          int* __restrict__ sums, int n) {
  __shared__ int buf[1024];
  int t = threadIdx.x;
  int idx = blockIdx.x * 1024 + t;
  int x = (idx < n) ? deg[idx] : 0;
  int v = x;
  buf[t] = v;
  __syncthreads();
  for (int off = 1; off < 1024; off <<= 1) {
    int a = (t >= off) ? buf[t - off] : 0;
    __syncthreads();
    v += a;
    buf[t] = v;
    __syncthreads();
  }
  if (idx < n) row_start[idx] = v - x;  // local exclusive
  if (t == 1023) sums[blockIdx.x] = v;  // chunk total
}

__global__ __launch_bounds__(1024) void scan_sums_kernel(int* __restrict__ sums,
                                                         int* __restrict__ row_start,
                                                         int nch, int n) {
  __shared__ int buf[1024];
  int t = threadIdx.x;
  int x = (t < nch) ? sums[t] : 0;
  int v = x;
  buf[t] = v;
  __syncthreads();
  for (int off = 1; off < 1024; off <<= 1) {
    int a = (t >= off) ? buf[t - off] : 0;
    __syncthreads();
    v += a;
    buf[t] = v;
    __syncthreads();
  }
  if (t < nch) sums[t] = v - x;        // exclusive chunk offsets
  if (t == 1023) row_start[n] = v;     // grand total
}

__global__ __launch_bounds__(1024) void scan_add_kernel(int* __restrict__ row_start,
                                                        const int* __restrict__ sums, int n) {
  int idx = blockIdx.x * 1024 + threadIdx.x;
  if (idx < n) row_start[idx] += sums[blockIdx.x];
}

__global__ void fill_kernel(const int* __restrict__ ei, int* __restrict__ cursor,
                            const int* __restrict__ row_start, int* __restrict__ csr_src,
                            int* __restrict__ csr_dst, int E, int N) {
  int i = blockIdx.x * blockDim.x + threadIdx.x;
  if (i >= E + N) return;
  int src, dst;
  if (i < E) { src = ei[i]; dst = ei[E + i]; } else { src = dst = i - E; }
  int pos = atomicAdd(&cursor[dst], 1);
  int slot = row_start[dst] + pos;
  csr_src[slot] = src;
  csr_dst[slot] = dst;
}

// ---------------------------------------------------------------- GEMM  Hbh = bf16(X @ W) head-major, fused alpha dots
// Hbh layout: [head][nrows][32 ch]  (64B rows -> L2-friendly per-head gathers)
__global__ __launch_bounds__(256) void gemm_kernel(const float* __restrict__ X,
                                                   const float* __restrict__ W,
                                                   unsigned short* __restrict__ Hbh,
                                                   const float* __restrict__ a_src,
                                                   const float* __restrict__ a_dst,
                                                   float* __restrict__ as_arr,
                                                   float* __restrict__ ad_arr,
                                                   int nrows, int K) {
  __shared__ float Xs[64][36];    // 64 rows x 32 k, stride 36
  __shared__ float Ws[32][132];   // 32 k x 128 cols, stride 132
  int t = threadIdx.x;
  int row0 = blockIdx.x * 64;
  int tcol = t & 31;   // 32 col-groups of 4 cols
  int trow = t >> 5;   // 8 row-groups; rows trow + 8*i
  float acc[8][4];
#pragma unroll
  for (int i = 0; i < 8; ++i)
#pragma unroll
    for (int j = 0; j < 4; ++j) acc[i][j] = 0.0f;

  for (int kb = 0; kb < K; kb += 32) {
#pragma unroll
    for (int p = 0; p < 2; ++p) {       // X tile: 64x32 = 512 float4
      int flat = t + p * 256;
      int r = flat >> 3;
      int kq = (flat & 7) * 4;
      float4 v = make_float4(0.f, 0.f, 0.f, 0.f);
      int gr = row0 + r;
      if (gr < nrows) v = *(const float4*)(X + (size_t)gr * K + kb + kq);
      *(float4*)(&Xs[r][kq]) = v;
    }
#pragma unroll
    for (int p = 0; p < 4; ++p) {       // W tile: 32x128 = 1024 float4
      int flat = t + p * 256;
      int r = flat >> 5;
      int cq = (flat & 31) * 4;
      float4 v = *(const float4*)(W + (size_t)(kb + r) * 128 + cq);
      *(float4*)(&Ws[r][cq]) = v;
    }
    __syncthreads();
#pragma unroll
    for (int kk = 0; kk < 32; kk += 4) {
      float4 xv[8];
#pragma unroll
      for (int i = 0; i < 8; ++i) xv[i] = *(const float4*)(&Xs[trow + 8 * i][kk]);
#pragma unroll
      for (int q = 0; q < 4; ++q) {
        float4 wv = *(const float4*)(&Ws[kk + q][tcol * 4]);
#pragma unroll
        for (int i = 0; i < 8; ++i) {
          float xq = (q == 0) ? xv[i].x : (q == 1) ? xv[i].y : (q == 2) ? xv[i].z : xv[i].w;
          acc[i][0] += xq * wv.x;
          acc[i][1] += xq * wv.y;
          acc[i][2] += xq * wv.z;
          acc[i][3] += xq * wv.w;
        }
      }
    }
    __syncthreads();
  }

  // store bf16 H (head-major) + fused per-head alpha dots
  float4 as4 = *(const float4*)(a_src + tcol * 4);
  float4 ad4 = *(const float4*)(a_dst + tcol * 4);
  int head = tcol >> 3, sub = tcol & 7;   // 4 channels sub*4.. within head's 32
  float ps[8], pd[8];
#pragma unroll
  for (int i = 0; i < 8; ++i) {
    int r = row0 + trow + 8 * i;
    if (r < nrows) {
      union { unsigned short u[4]; uint2 v; } pk;
      pk.u[0] = f2bf(acc[i][0]);
      pk.u[1] = f2bf(acc[i][1]);
      pk.u[2] = f2bf(acc[i][2]);
      pk.u[3] = f2bf(acc[i][3]);
      *(uint2*)(Hbh + ((size_t)head * nrows + r) * 32 + sub * 4) = pk.v;
    }
    ps[i] = acc[i][0] * as4.x + acc[i][1] * as4.y + acc[i][2] * as4.z + acc[i][3] * as4.w;
    pd[i] = acc[i][0] * ad4.x + acc[i][1] * ad4.y + acc[i][2] * ad4.z + acc[i][3] * ad4.w;
  }
#pragma unroll
  for (int off = 1; off < 8; off <<= 1) {
#pragma unroll
    for (int i = 0; i < 8; ++i) {
      ps[i] += __shfl_xor(ps[i], off);
      pd[i] += __shfl_xor(pd[i], off);
    }
  }
  if (sub == 0) {
#pragma unroll
    for (int i = 0; i < 8; ++i) {
      int r = row0 + trow + 8 * i;
      if (r < nrows) {
        as_arr[(size_t)r * 4 + head] = ps[i];
        ad_arr[(size_t)r * 4 + head] = pd[i];
      }
    }
  }
}

// ---------------------------------------------------------------- per-edge exp(leaky(logit)), head-plane layout
// eh[head][edge] -- coalesced reads in agg's per-head loops
__global__ __launch_bounds__(256) void ecomp_kernel(const int* __restrict__ csr_src,
                                                    const int* __restrict__ csr_dst,
                                                    const float* __restrict__ as_arr,
                                                    const float* __restrict__ ad_arr,
                                                    float* __restrict__ eh, int Etot) {
  int i = blockIdx.x * 256 + threadIdx.x;
  if (i >= Etot) return;
  int s = csr_src[i];
  int d = csr_dst[i];
  float4 a = *(const float4*)(as_arr + (size_t)s * 4);
  float4 b = *(const float4*)(ad_arr + (size_t)d * 4);
  eh[i]                    = __expf(fminf(leaky(a.x + b.x), 80.f));
  eh[(size_t)Etot + i]     = __expf(fminf(leaky(a.y + b.y), 80.f));
  eh[(size_t)2 * Etot + i] = __expf(fminf(leaky(a.z + b.z), 80.f));
  eh[(size_t)3 * Etot + i] = __expf(fminf(leaky(a.w + b.w), 80.f));
}

// ---------------------------------------------------------------- aggregation v6: head-sequential, L2-resident gathers
// wave per node; per head: lane q=lane>>4 handles edge slots i+q, i+4+q;
// ql=lane&15 owns packed channel pair (2ql,2ql+1) of the head's 32 channels.
// One gather instr = 4 edges x one 64B line (L2-resident: 3.2MB/head).
template <int POOL>
__global__ __launch_bounds__(256) void agg_kernel(const unsigned short* __restrict__ Hbh,
                                                  const float* __restrict__ eh,
                                                  const int* __restrict__ csr_src,
                                                  const int* __restrict__ row_start,
                                                  const float* __restrict__ bias,
                                                  float* __restrict__ xnext,
                                                  const int* __restrict__ batch,
                                                  float* __restrict__ pooled,
                                                  int N, int Etot) {
  int wid = threadIdx.x >> 6;
  int lane = threadIdx.x & 63;
  int q = lane >> 4, ql = lane & 15;
  int n = blockIdx.x * 4 + wid;
  if (n >= N) return;
  int rs = row_start[n], re = row_start[n + 1];
  int g = POOL ? batch[n] : 0;

#pragma unroll
  for (int h = 0; h < 4; ++h) {
    const unsigned* hb = (const unsigned*)Hbh + (size_t)h * N * 16 + ql;  // row = 16 dwords
    const float* ep = eh + (size_t)h * Etot;
    float acc0 = 0.f, acc1 = 0.f, den = 0.f;
    for (int i = rs; i < re; i += 8) {
      int i0 = i + q, i1 = i + 4 + q;
      int j0 = i0 < re ? i0 : rs;            // safe slot (deg>=1 from self-loop)
      int j1 = i1 < re ? i1 : rs;
      int s0 = csr_src[j0], s1 = csr_src[j1];
      float e0 = i0 < re ? ep[j0] : 0.f;
      float e1 = i1 < re ? ep[j1] : 0.f;
      unsigned u0 = hb[(size_t)s0 * 16];
      unsigned u1 = hb[(size_t)s1 * 16];
      float2 f0 = bf2f2(u0), f1 = bf2f2(u1);
      den += e0 + e1;
      acc0 += e0 * f0.x + e1 * f1.x;
      acc1 += e0 * f0.y + e1 * f1.y;
    }
    // cross-quarter reduce (quarters hold disjoint edge subsets of same node)
    acc0 += __shfl_xor(acc0, 16); acc0 += __shfl_xor(acc0, 32);
    acc1 += __shfl_xor(acc1, 16); acc1 += __shfl_xor(acc1, 32);
    den  += __shfl_xor(den, 16);  den  += __shfl_xor(den, 32);
    if (q == 0) {
      float inv = 1.0f / (den + 1e-16f);
      int ch = h * 32 + 2 * ql;
      float2 bv = *(const float2*)(bias + ch);
      float v0 = leaky(acc0 * inv + bv.x);
      float v1 = leaky(acc1 * inv + bv.y);
      if (POOL) {
        atomicAdd(&pooled[(size_t)g * 128 + ch], v0);
        atomicAdd(&pooled[(size_t)g * 128 + ch + 1], v1);
      } else {
        *(float2*)(xnext + (size_t)n * 128 + ch) = make_float2(v0, v1);
      }
    }
  }
}

// ---------------------------------------------------------------- head
__global__ void head_kernel(const float* __restrict__ pooled, const float* __restrict__ fc_w,
                            const float* __restrict__ fc_b, const float* __restrict__ bn_g,
                            const float* __restrict__ bn_b, float* __restrict__ out, int G) {
  int t = threadIdx.x;
  int g = blockIdx.x * 8 + (t >> 5);
  int j = t & 31;
  if (g >= G) return;
  const float* pr = pooled + (size_t)g * 128;
  float acc = 0.f;
#pragma unroll 8
  for (int k = 0; k < 128; ++k) acc += pr[k] * fc_w[k * 32 + j];
  const float inv = 0.9999950000374997f;  // 1/sqrt(1+1e-5)
  out[g * 32 + j] = bn_g[j] * (acc + fc_b[j]) * inv + bn_b[j];
}

// ---------------------------------------------------------------- launch
extern "C" void kernel_launch(void* const* d_in, const int* in_sizes, int n_in,
                              void* d_out, int out_size, void* d_ws, size_t ws_size,
                              hipStream_t stream) {
  const float* x = (const float*)d_in[0];
  const int* ei = (const int*)d_in[1];
  const int* batch = (const int*)d_in[2];
  const float* Wm[3] = {(const float*)d_in[3], (const float*)d_in[7], (const float*)d_in[11]};
  const float* a_s[3] = {(const float*)d_in[4], (const float*)d_in[8], (const float*)d_in[12]};
  const float* a_d[3] = {(const float*)d_in[5], (const float*)d_in[9], (const float*)d_in[13]};
  const float* bb[3] = {(const float*)d_in[6], (const float*)d_in[10], (const float*)d_in[14]};
  const float* fc_w = (const float*)d_in[15];
  const float* fc_b = (const float*)d_in[16];
  const float* bn_g = (const float*)d_in[17];
  const float* bn_b = (const float*)d_in[18];
  float* out = (float*)d_out;

  int N = in_sizes[0] / 64;
  int E = in_sizes[1] / 2;
  int G = out_size / 32;
  int Etot = E + N;

  char* p = (char*)d_ws;
  auto carve = [&](size_t bytes) {
    char* r = p;
    p += (bytes + 255) & ~size_t(255);
    return r;
  };
  int* deg       = (int*)carve((size_t)N * 4);
  int* cursor    = (int*)carve((size_t)N * 4);
  float* pooled  = (float*)carve((size_t)G * 128 * 4);
  int* row_start = (int*)carve((size_t)(N + 1) * 4);
  int* sums      = (int*)carve(4096);
  int* csr_src   = (int*)carve((size_t)Etot * 4);
  int* csr_dst   = (int*)carve((size_t)Etot * 4);
  float* eh      = (float*)carve((size_t)Etot * 4 * 4);              // per-edge exp, head planes
  unsigned short* Hbh = (unsigned short*)carve((size_t)N * 128 * 2); // bf16 features, head-major
  float* bufX    = (float*)carve((size_t)N * 128 * 4);               // fp32 layer input
  float* as_arr  = (float*)carve((size_t)N * 4 * 4);
  float* ad_arr  = (float*)carve((size_t)N * 4 * 4);

  // zero deg+cursor+pooled (contiguous carve region, pads included)
  int nz = (int)(((char*)(pooled + (size_t)G * 128) - (char*)deg) / 4);
  zero_kernel<<<512, 256, 0, stream>>>(deg, nz);

  // CSR build (dst-grouped)
  int egrid = (Etot + 255) / 256;
  count_kernel<<<egrid, 256, 0, stream>>>(ei, deg, E, N);
  int nch = (N + 1023) / 1024;
  scan_block_kernel<<<nch, 1024, 0, stream>>>(deg, row_start, sums, N);
  scan_sums_kernel<<<1, 1024, 0, stream>>>(sums, row_start, nch, N);
  scan_add_kernel<<<nch, 1024, 0, stream>>>(row_start, sums, N);
  fill_kernel<<<egrid, 256, 0, stream>>>(ei, cursor, row_start, csr_src, csr_dst, E, N);

  int ggrid = (N + 63) / 64;
  int ngrid = (N + 3) / 4;

  // layer 0 (K=64)
  gemm_kernel<<<ggrid, 256, 0, stream>>>(x, Wm[0], Hbh, a_s[0], a_d[0], as_arr, ad_arr, N, 64);
  ecomp_kernel<<<egrid, 256, 0, stream>>>(csr_src, csr_dst, as_arr, ad_arr, eh, Etot);
  agg_kernel<0><<<ngrid, 256, 0, stream>>>(Hbh, eh, csr_src, row_start, bb[0],
                                           bufX, nullptr, nullptr, N, Etot);
  // layer 1 (K=128)
  gemm_kernel<<<ggrid, 256, 0, stream>>>(bufX, Wm[1], Hbh, a_s[1], a_d[1], as_arr, ad_arr, N, 128);
  ecomp_kernel<<<egrid, 256, 0, stream>>>(csr_src, csr_dst, as_arr, ad_arr, eh, Etot);
  agg_kernel<0><<<ngrid, 256, 0, stream>>>(Hbh, eh, csr_src, row_start, bb[1],
                                           bufX, nullptr, nullptr, N, Etot);
  // layer 2 (K=128), fused pooling
  gemm_kernel<<<ggrid, 256, 0, stream>>>(bufX, Wm[2], Hbh, a_s[2], a_d[2], as_arr, ad_arr, N, 128);
  ecomp_kernel<<<egrid, 256, 0, stream>>>(csr_src, csr_dst, as_arr, ad_arr, eh, Etot);
  agg_kernel<1><<<ngrid, 256, 0, stream>>>(Hbh, eh, csr_src, row_start, bb[2],
                                           nullptr, batch, pooled, N, Etot);

  head_kernel<<<(G + 7) / 8, 256, 0, stream>>>(pooled, fc_w, fc_b, bn_g, bn_b, out, G);
}

// Round 7
// 491.244 us; speedup vs baseline: 1.2095x; 1.2095x over previous
//
#include <hip/hip_runtime.h>
#include <hip/hip_bf16.h>
#include <float.h>

#define NEG 0.2f

__device__ __forceinline__ float leaky(float x) { return x > 0.0f ? x : NEG * x; }

__device__ __forceinline__ unsigned short f2bf(float f) {
  unsigned x = __float_as_uint(f);
  unsigned r = (x + 0x7fffu + ((x >> 16) & 1u)) >> 16;  // round-to-nearest-even
  return (unsigned short)r;
}

__device__ __forceinline__ float2 bf2f2(unsigned u) {   // u = (ch1<<16)|ch0
  float2 r;
  r.x = __uint_as_float(u << 16);
  r.y = __uint_as_float(u & 0xffff0000u);
  return r;
}

// ---------------------------------------------------------------- utilities
__global__ void zero_kernel(int* __restrict__ p, int n) {
  int i = blockIdx.x * blockDim.x + threadIdx.x;
  int stride = gridDim.x * blockDim.x;
  for (; i < n; i += stride) p[i] = 0;
}

__global__ void count_kernel(const int* __restrict__ ei, int* __restrict__ deg, int E, int N) {
  int i = blockIdx.x * blockDim.x + threadIdx.x;
  if (i >= E + N) return;
  int dst = (i < E) ? ei[E + i] : (i - E);
  atomicAdd(&deg[dst], 1);
}

__global__ __launch_bounds__(1024) void scan_block_kernel(const int* __restrict__ deg,
                                                          int* __restrict__ row_start,
                                                          int* __restrict__ sums, int n) {
  __shared__ int buf[1024];
  int t = threadIdx.x;
  int idx = blockIdx.x * 1024 + t;
  int x = (idx < n) ? deg[idx] : 0;
  int v = x;
  buf[t] = v;
  __syncthreads();
  for (int off = 1; off < 1024; off <<= 1) {
    int a = (t >= off) ? buf[t - off] : 0;
    __syncthreads();
    v += a;
    buf[t] = v;
    __syncthreads();
  }
  if (idx < n) row_start[idx] = v - x;  // local exclusive
  if (t == 1023) sums[blockIdx.x] = v;  // chunk total
}

__global__ __launch_bounds__(1024) void scan_sums_kernel(int* __restrict__ sums,
                                                         int* __restrict__ row_start,
                                                         int nch, int n) {
  __shared__ int buf[1024];
  int t = threadIdx.x;
  int x = (t < nch) ? sums[t] : 0;
  int v = x;
  buf[t] = v;
  __syncthreads();
  for (int off = 1; off < 1024; off <<= 1) {
    int a = (t >= off) ? buf[t - off] : 0;
    __syncthreads();
    v += a;
    buf[t] = v;
    __syncthreads();
  }
  if (t < nch) sums[t] = v - x;        // exclusive chunk offsets
  if (t == 1023) row_start[n] = v;     // grand total
}

__global__ __launch_bounds__(1024) void scan_add_kernel(int* __restrict__ row_start,
                                                        const int* __restrict__ sums, int n) {
  int idx = blockIdx.x * 1024 + threadIdx.x;
  if (idx < n) row_start[idx] += sums[blockIdx.x];
}

__global__ void fill_kernel(const int* __restrict__ ei, int* __restrict__ cursor,
                            const int* __restrict__ row_start, int* __restrict__ csr_src,
                            int* __restrict__ csr_dst, int E, int N) {
  int i = blockIdx.x * blockDim.x + threadIdx.x;
  if (i >= E + N) return;
  int src, dst;
  if (i < E) { src = ei[i]; dst = ei[E + i]; } else { src = dst = i - E; }
  int pos = atomicAdd(&cursor[dst], 1);
  int slot = row_start[dst] + pos;
  csr_src[slot] = src;
  csr_dst[slot] = dst;
}

// ---------------------------------------------------------------- GEMM  Hb = bf16(X @ W), fused alpha dots
__global__ __launch_bounds__(256) void gemm_kernel(const float* __restrict__ X,
                                                   const float* __restrict__ W,
                                                   unsigned short* __restrict__ Hb,
                                                   const float* __restrict__ a_src,
                                                   const float* __restrict__ a_dst,
                                                   float* __restrict__ as_arr,
                                                   float* __restrict__ ad_arr,
                                                   int nrows, int K) {
  __shared__ float Xs[64][36];    // 64 rows x 32 k, stride 36
  __shared__ float Ws[32][132];   // 32 k x 128 cols, stride 132
  int t = threadIdx.x;
  int row0 = blockIdx.x * 64;
  int tcol = t & 31;   // 32 col-groups of 4 cols
  int trow = t >> 5;   // 8 row-groups; rows trow + 8*i
  float acc[8][4];
#pragma unroll
  for (int i = 0; i < 8; ++i)
#pragma unroll
    for (int j = 0; j < 4; ++j) acc[i][j] = 0.0f;

  for (int kb = 0; kb < K; kb += 32) {
#pragma unroll
    for (int p = 0; p < 2; ++p) {       // X tile: 64x32 = 512 float4
      int flat = t + p * 256;
      int r = flat >> 3;
      int kq = (flat & 7) * 4;
      float4 v = make_float4(0.f, 0.f, 0.f, 0.f);
      int gr = row0 + r;
      if (gr < nrows) v = *(const float4*)(X + (size_t)gr * K + kb + kq);
      *(float4*)(&Xs[r][kq]) = v;
    }
#pragma unroll
    for (int p = 0; p < 4; ++p) {       // W tile: 32x128 = 1024 float4
      int flat = t + p * 256;
      int r = flat >> 5;
      int cq = (flat & 31) * 4;
      float4 v = *(const float4*)(W + (size_t)(kb + r) * 128 + cq);
      *(float4*)(&Ws[r][cq]) = v;
    }
    __syncthreads();
#pragma unroll
    for (int kk = 0; kk < 32; kk += 4) {
      float4 xv[8];
#pragma unroll
      for (int i = 0; i < 8; ++i) xv[i] = *(const float4*)(&Xs[trow + 8 * i][kk]);
#pragma unroll
      for (int q = 0; q < 4; ++q) {
        float4 wv = *(const float4*)(&Ws[kk + q][tcol * 4]);
#pragma unroll
        for (int i = 0; i < 8; ++i) {
          float xq = (q == 0) ? xv[i].x : (q == 1) ? xv[i].y : (q == 2) ? xv[i].z : xv[i].w;
          acc[i][0] += xq * wv.x;
          acc[i][1] += xq * wv.y;
          acc[i][2] += xq * wv.z;
          acc[i][3] += xq * wv.w;
        }
      }
    }
    __syncthreads();
  }

  // store bf16 H + fused per-head alpha dots
  float4 as4 = *(const float4*)(a_src + tcol * 4);
  float4 ad4 = *(const float4*)(a_dst + tcol * 4);
  float ps[8], pd[8];
#pragma unroll
  for (int i = 0; i < 8; ++i) {
    int r = row0 + trow + 8 * i;
    if (r < nrows) {
      union { unsigned short u[4]; uint2 v; } pk;
      pk.u[0] = f2bf(acc[i][0]);
      pk.u[1] = f2bf(acc[i][1]);
      pk.u[2] = f2bf(acc[i][2]);
      pk.u[3] = f2bf(acc[i][3]);
      *(uint2*)(Hb + (size_t)r * 128 + tcol * 4) = pk.v;
    }
    ps[i] = acc[i][0] * as4.x + acc[i][1] * as4.y + acc[i][2] * as4.z + acc[i][3] * as4.w;
    pd[i] = acc[i][0] * ad4.x + acc[i][1] * ad4.y + acc[i][2] * ad4.z + acc[i][3] * ad4.w;
  }
#pragma unroll
  for (int off = 1; off < 8; off <<= 1) {
#pragma unroll
    for (int i = 0; i < 8; ++i) {
      ps[i] += __shfl_xor(ps[i], off);
      pd[i] += __shfl_xor(pd[i], off);
    }
  }
  if ((tcol & 7) == 0) {
    int head = tcol >> 3;
#pragma unroll
    for (int i = 0; i < 8; ++i) {
      int r = row0 + trow + 8 * i;
      if (r < nrows) {
        as_arr[(size_t)r * 4 + head] = ps[i];
        ad_arr[(size_t)r * 4 + head] = pd[i];
      }
    }
  }
}

// ---------------------------------------------------------------- per-edge exp(leaky(logit)) for all 4 heads
__global__ __launch_bounds__(256) void ecomp_kernel(const int* __restrict__ csr_src,
                                                    const int* __restrict__ csr_dst,
                                                    const float* __restrict__ as_arr,
                                                    const float* __restrict__ ad_arr,
                                                    float* __restrict__ earr, int Etot) {
  int i = blockIdx.x * 256 + threadIdx.x;
  if (i >= Etot) return;
  int s = csr_src[i];
  int d = csr_dst[i];
  float4 a = *(const float4*)(as_arr + (size_t)s * 4);
  float4 b = *(const float4*)(ad_arr + (size_t)d * 4);
  float4 e;
  e.x = __expf(fminf(leaky(a.x + b.x), 80.f));
  e.y = __expf(fminf(leaky(a.y + b.y), 80.f));
  e.z = __expf(fminf(leaky(a.z + b.z), 80.f));
  e.w = __expf(fminf(leaky(a.w + b.w), 80.f));
  *(float4*)(earr + (size_t)i * 4) = e;
}

// ---------------------------------------------------------------- aggregation v7
// wave per node (R5 layout: lane owns channels 2l,2l+1 of node-major 256B rows).
// Per 16-edge group: 1 coalesced idx load + 1 coalesced e load (16 edges x 4 heads),
// values distributed via __shfl (register path, no LDS/waitcnt). All 16 row-gathers
// issued back-to-back (16-deep MLP); next group's idx/e prefetched during gathers.
// Tail slots clamp to first edge's row (L1-hot) with e=0.
template <int POOL>
__global__ __launch_bounds__(256) void agg_kernel(const unsigned short* __restrict__ Hb,
                                                  const float* __restrict__ earr,
                                                  const int* __restrict__ csr_src,
                                                  const int* __restrict__ row_start,
                                                  const float* __restrict__ bias,
                                                  float* __restrict__ xnext,
                                                  const int* __restrict__ batch,
                                                  float* __restrict__ pooled, int N) {
  int wid = threadIdx.x >> 6;
  int lane = threadIdx.x & 63;
  int head = lane >> 4;
  int n = blockIdx.x * 4 + wid;
  if (n >= N) return;
  int rs = row_start[n], re = row_start[n + 1];
  int deg = re - rs;
  const unsigned* hp = (const unsigned*)Hb + lane;  // lane's packed channel pair
  float denom = 0.f, acc0 = 0.f, acc1 = 0.f;

  // group-0 idx/e loads
  int pos0 = rs + (lane & 15);
  int idxv = csr_src[pos0 < re ? pos0 : rs];
  int fp0 = rs * 4 + lane;
  float ev = fp0 < re * 4 ? earr[fp0] : 0.f;

  for (int base = 0; base < deg; base += 16) {
    // issue all 16 gathers for this group
    unsigned ug[16];
#pragma unroll
    for (int j = 0; j < 16; ++j) {
      int sidx = __shfl(idxv, j);
      ug[j] = hp[(size_t)sidx * 64];
    }
    // prefetch next group's idx/e (clamped; independent of gathers)
    int nb = rs + base + 16;
    int pos = nb + (lane & 15);
    int nidxv = csr_src[pos < re ? pos : rs];
    int fp = nb * 4 + lane;
    float nev = fp < re * 4 ? earr[fp] : 0.f;
    // accumulate current group
#pragma unroll
    for (int j = 0; j < 16; ++j) {
      float eh = __shfl(ev, j * 4 + head);
      float2 f = bf2f2(ug[j]);
      denom += eh;
      acc0 += eh * f.x;
      acc1 += eh * f.y;
    }
    idxv = nidxv;
    ev = nev;
  }

  float inv = 1.0f / (denom + 1e-16f);
  float2 bv = *(const float2*)(bias + 2 * lane);
  float v0 = leaky(acc0 * inv + bv.x);
  float v1 = leaky(acc1 * inv + bv.y);
  if (POOL) {
    int g = batch[n];
    atomicAdd(&pooled[(size_t)g * 128 + 2 * lane], v0);
    atomicAdd(&pooled[(size_t)g * 128 + 2 * lane + 1], v1);
  } else {
    *(float2*)(xnext + (size_t)n * 128 + 2 * lane) = make_float2(v0, v1);
  }
}

// ---------------------------------------------------------------- head
__global__ void head_kernel(const float* __restrict__ pooled, const float* __restrict__ fc_w,
                            const float* __restrict__ fc_b, const float* __restrict__ bn_g,
                            const float* __restrict__ bn_b, float* __restrict__ out, int G) {
  int t = threadIdx.x;
  int g = blockIdx.x * 8 + (t >> 5);
  int j = t & 31;
  if (g >= G) return;
  const float* pr = pooled + (size_t)g * 128;
  float acc = 0.f;
#pragma unroll 8
  for (int k = 0; k < 128; ++k) acc += pr[k] * fc_w[k * 32 + j];
  const float inv = 0.9999950000374997f;  // 1/sqrt(1+1e-5)
  out[g * 32 + j] = bn_g[j] * (acc + fc_b[j]) * inv + bn_b[j];
}

// ---------------------------------------------------------------- launch
extern "C" void kernel_launch(void* const* d_in, const int* in_sizes, int n_in,
                              void* d_out, int out_size, void* d_ws, size_t ws_size,
                              hipStream_t stream) {
  const float* x = (const float*)d_in[0];
  const int* ei = (const int*)d_in[1];
  const int* batch = (const int*)d_in[2];
  const float* Wm[3] = {(const float*)d_in[3], (const float*)d_in[7], (const float*)d_in[11]};
  const float* a_s[3] = {(const float*)d_in[4], (const float*)d_in[8], (const float*)d_in[12]};
  const float* a_d[3] = {(const float*)d_in[5], (const float*)d_in[9], (const float*)d_in[13]};
  const float* bb[3] = {(const float*)d_in[6], (const float*)d_in[10], (const float*)d_in[14]};
  const float* fc_w = (const float*)d_in[15];
  const float* fc_b = (const float*)d_in[16];
  const float* bn_g = (const float*)d_in[17];
  const float* bn_b = (const float*)d_in[18];
  float* out = (float*)d_out;

  int N = in_sizes[0] / 64;
  int E = in_sizes[1] / 2;
  int G = out_size / 32;
  int Etot = E + N;

  char* p = (char*)d_ws;
  auto carve = [&](size_t bytes) {
    char* r = p;
    p += (bytes + 255) & ~size_t(255);
    return r;
  };
  int* deg       = (int*)carve((size_t)N * 4);
  int* cursor    = (int*)carve((size_t)N * 4);
  float* pooled  = (float*)carve((size_t)G * 128 * 4);
  int* row_start = (int*)carve((size_t)(N + 1) * 4);
  int* sums      = (int*)carve(4096);
  int* csr_src   = (int*)carve((size_t)Etot * 4);
  int* csr_dst   = (int*)carve((size_t)Etot * 4);
  float* earr    = (float*)carve((size_t)Etot * 4 * 4);              // per-edge exp, 4 heads
  unsigned short* Hb = (unsigned short*)carve((size_t)N * 128 * 2);  // bf16 features
  float* bufX    = (float*)carve((size_t)N * 128 * 4);               // fp32 layer input
  float* as_arr  = (float*)carve((size_t)N * 4 * 4);
  float* ad_arr  = (float*)carve((size_t)N * 4 * 4);

  // zero deg+cursor+pooled (contiguous carve region, pads included)
  int nz = (int)(((char*)(pooled + (size_t)G * 128) - (char*)deg) / 4);
  zero_kernel<<<512, 256, 0, stream>>>(deg, nz);

  // CSR build (dst-grouped)
  int egrid = (Etot + 255) / 256;
  count_kernel<<<egrid, 256, 0, stream>>>(ei, deg, E, N);
  int nch = (N + 1023) / 1024;
  scan_block_kernel<<<nch, 1024, 0, stream>>>(deg, row_start, sums, N);
  scan_sums_kernel<<<1, 1024, 0, stream>>>(sums, row_start, nch, N);
  scan_add_kernel<<<nch, 1024, 0, stream>>>(row_start, sums, N);
  fill_kernel<<<egrid, 256, 0, stream>>>(ei, cursor, row_start, csr_src, csr_dst, E, N);

  int ggrid = (N + 63) / 64;
  int ngrid = (N + 3) / 4;

  // layer 0 (K=64)
  gemm_kernel<<<ggrid, 256, 0, stream>>>(x, Wm[0], Hb, a_s[0], a_d[0], as_arr, ad_arr, N, 64);
  ecomp_kernel<<<egrid, 256, 0, stream>>>(csr_src, csr_dst, as_arr, ad_arr, earr, Etot);
  agg_kernel<0><<<ngrid, 256, 0, stream>>>(Hb, earr, csr_src, row_start, bb[0],
                                           bufX, nullptr, nullptr, N);
  // layer 1 (K=128)
  gemm_kernel<<<ggrid, 256, 0, stream>>>(bufX, Wm[1], Hb, a_s[1], a_d[1], as_arr, ad_arr, N, 128);
  ecomp_kernel<<<egrid, 256, 0, stream>>>(csr_src, csr_dst, as_arr, ad_arr, earr, Etot);
  agg_kernel<0><<<ngrid, 256, 0, stream>>>(Hb, earr, csr_src, row_start, bb[1],
                                           bufX, nullptr, nullptr, N);
  // layer 2 (K=128), fused pooling
  gemm_kernel<<<ggrid, 256, 0, stream>>>(bufX, Wm[2], Hb, a_s[2], a_d[2], as_arr, ad_arr, N, 128);
  ecomp_kernel<<<egrid, 256, 0, stream>>>(csr_src, csr_dst, as_arr, ad_arr, earr, Etot);
  agg_kernel<1><<<ngrid, 256, 0, stream>>>(Hb, earr, csr_src, row_start, bb[2],
                                           nullptr, batch, pooled, N);

  head_kernel<<<(G + 7) / 8, 256, 0, stream>>>(pooled, fc_w, fc_b, bn_g, bn_b, out, G);
}